// Round 1
// baseline (234.362 us; speedup 1.0000x reference)
//
#include <hip/hip_runtime.h>

// RoiAlign (TF crop_and_resize style), fp32, NHWC.
// features: [B,H,W,C] = [2,64,64,256]; rois: [B,N,4] = [2,2000,4]
// out: [B,N,7,7,C]
//
// One wave (64 lanes) per output pixel (b,n,py,px); C=256 -> float4/lane.
// Memory-bound on the ~200 MB output write; feature reads hit L2/L3.

#define POOL 7

__global__ __launch_bounds__(256) void roialign_kernel(
    const float* __restrict__ feat,   // [B,H,W,C]
    const float* __restrict__ rois,   // [B,N,4]
    float* __restrict__ out,          // [B,N,POOL,POOL,C]
    int B, int H, int W, int C, int N)
{
    const int lane = threadIdx.x & 63;
    const int wid  = threadIdx.x >> 6;                      // wave within block (0..3)
    const long long w = (long long)blockIdx.x * 4 + wid;    // global pixel id
    const long long total = (long long)B * N * POOL * POOL;
    if (w >= total) return;

    // Decompose pixel id -> (b, n, py, px)
    const int pp = (int)(w % (POOL * POOL));
    const long long bn = w / (POOL * POOL);
    const int px = pp % POOL;
    const int py = pp / POOL;
    const int n  = (int)(bn % N);
    const int b  = (int)(bn / N);

    // Wave-uniform roi load (compiler scalarizes; all lanes same address)
    const float* r = rois + ((long long)b * N + n) * 4;
    const float ry1 = r[0], rx1 = r[1], ry2 = r[2], rx2 = r[3];

    // Sample coordinates, matching reference arithmetic order
    const float fy = (float)py / (float)(POOL - 1);
    const float fx = (float)px / (float)(POOL - 1);
    const float ys = (ry1 + fy * (ry2 - ry1)) * (float)(H - 1);
    const float xs = (rx1 + fx * (rx2 - rx1)) * (float)(W - 1);

    const float y0f = fminf(fmaxf(floorf(ys), 0.0f), (float)(H - 1));
    const float x0f = fminf(fmaxf(floorf(xs), 0.0f), (float)(W - 1));
    const int y0 = (int)y0f;
    const int x0 = (int)x0f;
    const int y1i = min(y0 + 1, H - 1);
    const int x1i = min(x0 + 1, W - 1);
    const float wy = ys - y0f;
    const float wx = xs - x0f;

    // float4 over channels: C=256 -> C4=64 == wave width
    const int C4 = C >> 2;
    const float4* fb = (const float4*)(feat + (long long)b * H * W * C);

    const long long i00 = ((long long)y0  * W + x0 ) * C4 + lane;
    const long long i01 = ((long long)y0  * W + x1i) * C4 + lane;
    const long long i10 = ((long long)y1i * W + x0 ) * C4 + lane;
    const long long i11 = ((long long)y1i * W + x1i) * C4 + lane;

    const float4 f00 = fb[i00];
    const float4 f01 = fb[i01];
    const float4 f10 = fb[i10];
    const float4 f11 = fb[i11];

    float4 o;
    {
        // top = f00 + (f01-f00)*wx; bot = f10 + (f11-f10)*wx; o = top + (bot-top)*wy
        float tx, bx;
        tx = f00.x + (f01.x - f00.x) * wx;
        bx = f10.x + (f11.x - f10.x) * wx;
        o.x = tx + (bx - tx) * wy;
        tx = f00.y + (f01.y - f00.y) * wx;
        bx = f10.y + (f11.y - f10.y) * wx;
        o.y = tx + (bx - tx) * wy;
        tx = f00.z + (f01.z - f00.z) * wx;
        bx = f10.z + (f11.z - f10.z) * wx;
        o.z = tx + (bx - tx) * wy;
        tx = f00.w + (f01.w - f00.w) * wx;
        bx = f10.w + (f11.w - f10.w) * wx;
        o.w = tx + (bx - tx) * wy;
    }

    ((float4*)out)[w * C4 + lane] = o;
}

extern "C" void kernel_launch(void* const* d_in, const int* in_sizes, int n_in,
                              void* d_out, int out_size, void* d_ws, size_t ws_size,
                              hipStream_t stream) {
    const int B = 2, H = 64, W = 64, C = 256;
    const int N = in_sizes[1] / (B * 4);   // rois flat = B*N*4

    const float* feat = (const float*)d_in[0];
    const float* rois = (const float*)d_in[1];
    float* out = (float*)d_out;

    const long long total_pixels = (long long)B * N * POOL * POOL;  // 196000
    const int waves_per_block = 4;                                   // 256 threads
    const int blocks = (int)((total_pixels + waves_per_block - 1) / waves_per_block);

    roialign_kernel<<<blocks, 256, 0, stream>>>(feat, rois, out, B, H, W, C, N);
}

// Round 2
// 218.060 us; speedup vs baseline: 1.0748x; 1.0748x over previous
//
#include <hip/hip_runtime.h>

// RoiAlign (TF crop_and_resize style), fp32, NHWC.
// features: [B,H,W,C] = [2,64,64,256]; rois: [B,N,4] = [2,2000,4]
// out: [B,N,7,7,C]
//
// One wave (64 lanes) per output ROW (b,n,py): loops px=0..6, 4 corner
// float4 loads + lerp + 1 float4 store per px. C=256 -> 64 float4 = wave.
//
// XCD swizzle: blockIdx%8 in {0..3} -> batch 0, {4..7} -> batch 1, so each
// XCD's 4 MiB L2 caches exactly one 4.19 MB feature image (whole working
// set resident -> ~100% L2 hits on the 784 MB of corner reads).

#define POOL 7

__global__ __launch_bounds__(256) void roialign_kernel(
    const float* __restrict__ feat,   // [B,H,W,C]
    const float* __restrict__ rois,   // [B,N,4]
    float* __restrict__ out,          // [B,N,POOL,POOL,C]
    int H, int W, int C4, int N, int blocks_per_batch)
{
    const int lane = threadIdx.x & 63;
    const int wid  = threadIdx.x >> 6;        // wave in block (0..3)

    // XCD-aware decomposition: xcd = blockIdx%8 (round-robin heuristic)
    const int xcd  = blockIdx.x & 7;
    const int slot = blockIdx.x >> 3;
    const int b    = xcd >> 2;                // batch image for this XCD
    const int lblock = slot * 4 + (xcd & 3);  // block index within batch
    if (lblock >= blocks_per_batch) return;

    const int row = lblock * 4 + wid;         // (n,py) row within batch
    const int rows_per_batch = N * POOL;
    if (row >= rows_per_batch) return;

    const int n  = row / POOL;
    const int py = row - n * POOL;

    // ROI load: all lanes same address -> one cacheline, broadcast
    const float* r = rois + ((long long)b * N + n) * 4;
    const float ry1 = r[0], rx1 = r[1], ry2 = r[2], rx2 = r[3];

    // y interpolation (row-uniform)
    const float fy = (float)py * (1.0f / (POOL - 1));
    const float ys = (ry1 + fy * (ry2 - ry1)) * (float)(H - 1);
    const float y0f = fminf(fmaxf(floorf(ys), 0.0f), (float)(H - 1));
    const int   y0  = (int)y0f;
    const int   y1i = min(y0 + 1, H - 1);
    const float wy  = ys - y0f;

    const float4* fb = (const float4*)feat + (long long)b * H * W * C4;
    const float4* r0 = fb + (long long)y0  * W * C4;
    const float4* r1 = fb + (long long)y1i * W * C4;

    float4* ob = (float4*)out +
                 (((long long)b * N + n) * (POOL * POOL) + (long long)py * POOL) * C4 + lane;

    const float dx = rx2 - rx1;

#pragma unroll
    for (int px = 0; px < POOL; ++px) {
        const float fx  = (float)px * (1.0f / (POOL - 1));
        const float xs  = (rx1 + fx * dx) * (float)(W - 1);
        const float x0f = fminf(fmaxf(floorf(xs), 0.0f), (float)(W - 1));
        const int   x0  = (int)x0f;
        const int   x1i = min(x0 + 1, W - 1);
        const float wx  = xs - x0f;

        const float4 f00 = r0[x0  * C4 + lane];
        const float4 f01 = r0[x1i * C4 + lane];
        const float4 f10 = r1[x0  * C4 + lane];
        const float4 f11 = r1[x1i * C4 + lane];

        float4 o;
        float tx, bx;
        tx = f00.x + (f01.x - f00.x) * wx;
        bx = f10.x + (f11.x - f10.x) * wx;
        o.x = tx + (bx - tx) * wy;
        tx = f00.y + (f01.y - f00.y) * wx;
        bx = f10.y + (f11.y - f10.y) * wx;
        o.y = tx + (bx - tx) * wy;
        tx = f00.z + (f01.z - f00.z) * wx;
        bx = f10.z + (f11.z - f10.z) * wx;
        o.z = tx + (bx - tx) * wy;
        tx = f00.w + (f01.w - f00.w) * wx;
        bx = f10.w + (f11.w - f10.w) * wx;
        o.w = tx + (bx - tx) * wy;

        ob[px * C4] = o;
    }
}

extern "C" void kernel_launch(void* const* d_in, const int* in_sizes, int n_in,
                              void* d_out, int out_size, void* d_ws, size_t ws_size,
                              hipStream_t stream) {
    const int B = 2, H = 64, W = 64, C = 256;
    const int N = in_sizes[1] / (B * 4);   // rois flat = B*N*4

    const float* feat = (const float*)d_in[0];
    const float* rois = (const float*)d_in[1];
    float* out = (float*)d_out;

    const int rows_per_batch   = N * POOL;                    // 14000
    const int blocks_per_batch = (rows_per_batch + 3) / 4;    // 3500 (4 waves/block)
    // slots of 8 blocks: 4 per batch; round up so both batches covered
    const int slots  = (blocks_per_batch + 3) / 4;            // 875
    const int blocks = slots * 8;                             // 7000

    roialign_kernel<<<blocks, 256, 0, stream>>>(feat, rois, out,
                                                H, W, C / 4, N, blocks_per_batch);
}

// Round 3
// 217.010 us; speedup vs baseline: 1.0800x; 1.0048x over previous
//
#include <hip/hip_runtime.h>

// RoiAlign (TF crop_and_resize style), fp32, NHWC.
// features: [B,H,W,C] = [2,64,64,256]; rois: [B,N,4] = [2,2000,4]
// out: [B,N,7,7,C]
//
// One wave (64 lanes) per output ROW (b,n,py): loops px=0..6, 4 corner
// float4 loads + lerp + 1 nontemporal float4 store per px.
//
// XCD swizzle: blockIdx%8 in {0..3} -> batch 0, {4..7} -> batch 1, so each
// XCD's 4 MiB L2 caches one 4.19 MB feature image.
// Output stores are NONTEMPORAL (nt) so the 200 MB write stream does not
// evict the L2-resident feature image (R2 post-mortem: write pollution
// was defeating the swizzle).

#define POOL 7

typedef float vfloat4 __attribute__((ext_vector_type(4)));

__global__ __launch_bounds__(256) void roialign_kernel(
    const float* __restrict__ feat,   // [B,H,W,C]
    const float* __restrict__ rois,   // [B,N,4]
    float* __restrict__ out,          // [B,N,POOL,POOL,C]
    int H, int W, int C4, int N, int blocks_per_batch)
{
    const int lane = threadIdx.x & 63;
    const int wid  = threadIdx.x >> 6;        // wave in block (0..3)

    // XCD-aware decomposition: xcd = blockIdx%8 (round-robin heuristic)
    const int xcd  = blockIdx.x & 7;
    const int slot = blockIdx.x >> 3;
    const int b    = xcd >> 2;                // batch image for this XCD
    const int lblock = slot * 4 + (xcd & 3);  // block index within batch
    if (lblock >= blocks_per_batch) return;

    const int row = lblock * 4 + wid;         // (n,py) row within batch
    const int rows_per_batch = N * POOL;
    if (row >= rows_per_batch) return;

    const int n  = row / POOL;
    const int py = row - n * POOL;

    // ROI load: all lanes same address -> one cacheline, broadcast
    const float* r = rois + ((long long)b * N + n) * 4;
    const float ry1 = r[0], rx1 = r[1], ry2 = r[2], rx2 = r[3];

    // y interpolation (row-uniform)
    const float fy = (float)py * (1.0f / (POOL - 1));
    const float ys = (ry1 + fy * (ry2 - ry1)) * (float)(H - 1);
    const float y0f = fminf(fmaxf(floorf(ys), 0.0f), (float)(H - 1));
    const int   y0  = (int)y0f;
    const int   y1i = min(y0 + 1, H - 1);
    const float wy  = ys - y0f;

    const vfloat4* fb = (const vfloat4*)feat + (long long)b * H * W * C4;
    const vfloat4* r0 = fb + (long long)y0  * W * C4 + lane;
    const vfloat4* r1 = fb + (long long)y1i * W * C4 + lane;

    vfloat4* ob = (vfloat4*)out +
                  (((long long)b * N + n) * (POOL * POOL) + (long long)py * POOL) * C4 + lane;

    const float dx = rx2 - rx1;

#pragma unroll
    for (int px = 0; px < POOL; ++px) {
        const float fx  = (float)px * (1.0f / (POOL - 1));
        const float xs  = (rx1 + fx * dx) * (float)(W - 1);
        const float x0f = fminf(fmaxf(floorf(xs), 0.0f), (float)(W - 1));
        const int   x0  = (int)x0f;
        const int   x1i = min(x0 + 1, W - 1);
        const float wx  = xs - x0f;

        const vfloat4 f00 = r0[x0  * C4];
        const vfloat4 f01 = r0[x1i * C4];
        const vfloat4 f10 = r1[x0  * C4];
        const vfloat4 f11 = r1[x1i * C4];

        const vfloat4 top = f00 + (f01 - f00) * wx;
        const vfloat4 bot = f10 + (f11 - f10) * wx;
        const vfloat4 o   = top + (bot - top) * wy;

        __builtin_nontemporal_store(o, ob + px * C4);
    }
}

extern "C" void kernel_launch(void* const* d_in, const int* in_sizes, int n_in,
                              void* d_out, int out_size, void* d_ws, size_t ws_size,
                              hipStream_t stream) {
    const int B = 2, H = 64, W = 64, C = 256;
    const int N = in_sizes[1] / (B * 4);   // rois flat = B*N*4

    const float* feat = (const float*)d_in[0];
    const float* rois = (const float*)d_in[1];
    float* out = (float*)d_out;

    const int rows_per_batch   = N * POOL;                    // 14000
    const int blocks_per_batch = (rows_per_batch + 3) / 4;    // 3500 (4 waves/block)
    const int slots  = (blocks_per_batch + 3) / 4;            // 875
    const int blocks = slots * 8;                             // 7000

    roialign_kernel<<<blocks, 256, 0, stream>>>(feat, rois, out,
                                                H, W, C / 4, N, blocks_per_batch);
}